// Round 13
// baseline (185.594 us; speedup 1.0000x reference)
//
#include <hip/hip_runtime.h>
#include <math.h>

typedef __attribute__((ext_vector_type(4))) float f32x4;
typedef __attribute__((ext_vector_type(8))) short bf16x8;
typedef __attribute__((ext_vector_type(2))) _Float16 f16x2;
typedef __attribute__((ext_vector_type(8))) _Float16 f16x8;

#define HH 128
#define WW 128
#define HWSZ 16384
#define BHW 131072
#define BB 8
#define PIMG (130 * 130 * 8)   // padded image-plane ushorts per (b,cg)

__device__ __forceinline__ float bf2f(ushort u) {
    union { uint i; float f; } x; x.i = ((uint)u) << 16; return x.f;
}
__device__ __forceinline__ ushort f2bf(float f) {
    union { float f; uint i; } x; x.f = f;
    uint r = (x.i + 0x7fffu + ((x.i >> 16) & 1u)) >> 16;
    return (ushort)r;
}
__device__ __forceinline__ ushort f2h_bits(float f) {
    union { _Float16 h; ushort u; } x; x.h = (_Float16)f; return x.u;
}

// NCHW fp32 (C=64) -> group-planar 16-bit xg[b][cg][hw][8]. F16=0: bf16, 1: fp16.
template<int F16>
__global__ __launch_bounds__(256) void to_gp_k(const float* __restrict__ x,
                                               ushort* __restrict__ y) {
    __shared__ ushort lds[64][66];
    int blk = blockIdx.x;
    int b = blk >> 8;
    int hw0 = (blk & 255) << 6;
    int t = threadIdx.x;
    int lane = t & 63;
    int q = t >> 6;
#pragma unroll
    for (int i = 0; i < 16; i++) {
        int c = i * 4 + q;
        float v = x[((size_t)(b * 64 + c) << 14) + hw0 + lane];
        lds[c][lane] = F16 ? f2h_bits(v) : f2bf(v);
    }
    __syncthreads();
#pragma unroll
    for (int it = 0; it < 2; it++) {
        int id = it * 256 + t;
        int cg = id >> 6;
        int px = id & 63;
        uint pk[4];
#pragma unroll
        for (int j = 0; j < 4; j++)
            pk[j] = (uint)lds[cg * 8 + 2 * j][px] | ((uint)lds[cg * 8 + 2 * j + 1][px] << 16);
        *(uint4*)(y + ((((size_t)b * 8 + cg) << 14) + hw0 + px) * 8) = *(uint4*)pk;
    }
}

// NCHW fp32 (C=64) -> PADDED group-planar bf16 Pg[b][cg][130][130][8] (interior).
__global__ __launch_bounds__(256) void to_gp_pad_k(const float* __restrict__ x,
                                                   ushort* __restrict__ Pg) {
    __shared__ ushort lds[64][66];
    int blk = blockIdx.x;
    int b = blk >> 8;
    int hw0 = (blk & 255) << 6;
    int t = threadIdx.x;
    int lane = t & 63;
    int q = t >> 6;
#pragma unroll
    for (int i = 0; i < 16; i++) {
        int c = i * 4 + q;
        lds[c][lane] = f2bf(x[((size_t)(b * 64 + c) << 14) + hw0 + lane]);
    }
    __syncthreads();
#pragma unroll
    for (int it = 0; it < 2; it++) {
        int id = it * 256 + t;
        int cg = id >> 6;
        int px = id & 63;
        uint pk[4];
#pragma unroll
        for (int j = 0; j < 4; j++)
            pk[j] = (uint)lds[cg * 8 + 2 * j][px] | ((uint)lds[cg * 8 + 2 * j + 1][px] << 16);
        int hw = hw0 + px;
        int h = hw >> 7, w = hw & 127;
        *(uint4*)(Pg + ((size_t)((b * 8 + cg) * 130 + h + 1) * 130 + w + 1) * 8) = *(uint4*)pk;
    }
}

// Zero the 1-px halo of all 64 padded images in Pg.
__global__ __launch_bounds__(256) void halo_zero_k(ushort* __restrict__ Pg) {
    int idx = blockIdx.x * 256 + threadIdx.x;
    if (idx >= 64 * 516) return;
    int img = idx / 516, e = idx - img * 516;
    int r, c;
    if (e < 130)      { r = 0;           c = e; }
    else if (e < 260) { r = 129;         c = e - 130; }
    else if (e < 388) { r = e - 260 + 1; c = 0; }
    else              { r = e - 388 + 1; c = 129; }
    uint4 z = {0u, 0u, 0u, 0u};
    *(uint4*)(Pg + ((size_t)(img * 130 + r) * 130 + c) * 8) = z;
}

// w[Co][64][3][3] fp32 -> wa[Co_pad][576] 16-bit with r = kk*64+ci.
template<int F16>
__global__ __launch_bounds__(256) void prep_wa(const float* __restrict__ w,
                                               ushort* __restrict__ wa, int Co, int Co_pad) {
    int idx = blockIdx.x * 256 + threadIdx.x;
    if (idx >= Co_pad * 576) return;
    int co = idx / 576, r = idx % 576;
    int kk = r >> 6, ci = r & 63;
    ushort v = 0;
    if (co < Co) {
        float f = w[(co * 64 + ci) * 9 + kk];
        v = F16 ? f2h_bits(f) : f2bf(f);
    }
    wa[idx] = v;
}

// ---------------------------------------------------------------------------
// Fully-async 2-phase double-buffered implicit-GEMM 3x3 conv.
// Input: PADDED group-planar bf16 Pg (halo zeroed -> no predication).
// Per step: STAGE(t+1 -> buf^1) = 8 global_load_lds/wave (A rows + B row
// segments, both contiguous), then compute(t) from buf, then ONE barrier
// (its vmcnt(0) drain lands ~600cy after issue -> latency covered).
// B LDS layout [cg][px][8]: B-fragment = one 16B chunk, no swizzle needed.
// MODE 0: output padded group-planar bf16 (interior). MODE 1: dyx/mask planes.
// ---------------------------------------------------------------------------
template<int COT, int MODE>
__global__ __launch_bounds__(256, 2) void conv_pad_k(
    const ushort* __restrict__ Pg, const ushort* __restrict__ wa,
    const float* __restrict__ bias, ushort* __restrict__ Pgo,
    uint* __restrict__ dyxp, ushort* __restrict__ mpl, int Cout) {
    constexpr int WCO = COT / 4;     // co per wave
    constexpr int NN = WCO / 16;     // A fragment pairs per wave
    constexpr int NA = COT / 32;     // A gload_lds per wave
    constexpr int ABYTES = COT * 128;
    __shared__ ushort Al[2 * COT * 64];   // [buf][co][64ci], rows 128B, swizzled
    __shared__ ushort Bg[2 * 8192];       // [buf][cg][128px][8ch], linear
    int t = threadIdx.x;
    int orig = blockIdx.x;
    int blk = (orig & 7) * 128 + (orig >> 3);   // bijective, 1024 = 8*128; XCD = image
    int b = blk >> 7;
    int h = blk & 127;
    int cot = blockIdx.y;
    int lane = t & 63;
    int wv = t >> 6;
    int lg = lane >> 4;
    int lr = lane & 15;
    int rs = (lr & 7) << 4;                      // A read-side swizzle
    int asw = ((lane & 7) ^ (lane >> 3)) << 4;   // A source pre-swizzle
    const char* wab = (const char*)wa;

#define STAGE(KK, BI) do {                                                      \
    int ky_ = (KK) / 3, kx_ = (KK) - ky_ * 3;                                   \
    _Pragma("unroll")                                                           \
    for (int a = 0; a < NA; a++) {                                              \
        int rb = wv * WCO + a * 8;                                              \
        const char* g = wab + (size_t)(cot * COT + rb + (lane >> 3)) * 1152 + (KK) * 128 + asw; \
        __builtin_amdgcn_global_load_lds(                                       \
            (const __attribute__((address_space(1))) void*)g,                   \
            (__attribute__((address_space(3))) void*)((char*)Al + (BI) * ABYTES + rb * 128), \
            16, 0, 0);                                                          \
    }                                                                           \
    _Pragma("unroll")                                                           \
    for (int i = 0; i < 4; i++) {                                               \
        int u = i * 4 + wv;                                                     \
        int cg = u >> 1, hf = u & 1;                                            \
        const char* g = (const char*)Pg +                                       \
            ((size_t)((b * 8 + cg) * 130 + h + ky_) * 130 + kx_ + hf * 64 + lane) * 16; \
        __builtin_amdgcn_global_load_lds(                                       \
            (const __attribute__((address_space(1))) void*)g,                   \
            (__attribute__((address_space(3))) void*)((char*)Bg + (BI) * 16384 + (cg * 128 + hf * 64) * 16), \
            16, 0, 0);                                                          \
    } } while (0)

    f32x4 acc[NN][8];
#pragma unroll
    for (int n = 0; n < NN; n++)
#pragma unroll
        for (int j = 0; j < 8; j++) acc[n][j] = f32x4{0, 0, 0, 0};

    STAGE(0, 0);
    __syncthreads();

#pragma unroll 1
    for (int kk = 0; kk < 9; kk++) {
        int bi = kk & 1;
        if (kk < 8) STAGE(kk + 1, bi ^ 1);
        // ---- compute(kk) from buf bi ----
        bf16x8 a0[NN], a1[NN];
#pragma unroll
        for (int n = 0; n < NN; n++) {
            int ar = wv * WCO + n * 16 + lr;
            a0[n] = *(const bf16x8*)((char*)Al + bi * ABYTES + ar * 128 + ((lg * 16) ^ rs));
            a1[n] = *(const bf16x8*)((char*)Al + bi * ABYTES + ar * 128 + ((lg * 16 + 64) ^ rs));
        }
#pragma unroll
        for (int j = 0; j < 8; j++) {
            int pr = j * 16 + lr;
            bf16x8 b0 = *(const bf16x8*)((char*)Bg + bi * 16384 + (lg * 128 + pr) * 16);
            bf16x8 b1 = *(const bf16x8*)((char*)Bg + bi * 16384 + ((4 + lg) * 128 + pr) * 16);
#pragma unroll
            for (int n = 0; n < NN; n++) {
                acc[n][j] = __builtin_amdgcn_mfma_f32_16x16x32_bf16(a0[n], b0, acc[n][j], 0, 0, 0);
                acc[n][j] = __builtin_amdgcn_mfma_f32_16x16x32_bf16(a1[n], b1, acc[n][j], 0, 0, 0);
            }
        }
        __syncthreads();   // drains STAGE(kk+1) vmcnt after ~600cy of compute
    }
#undef STAGE

    // ---- epilogue: co = cot*COT + wv*WCO + n*16 + lg*4 + r, px = j*16 + lr ----
#pragma unroll
    for (int n = 0; n < NN; n++) {
        int co_g = cot * COT + wv * WCO + n * 16 + lg * 4;
        if (co_g < Cout) {
            float bs[4];
#pragma unroll
            for (int r = 0; r < 4; r++) bs[r] = bias[co_g + r];
#pragma unroll
            for (int j = 0; j < 8; j++) {
                int pxl = j * 16 + lr;
                int hw = (h << 7) + pxl;
                int bhw = (b << 14) + hw;
                if (MODE == 0) {
                    int cg = co_g >> 3, cs = co_g & 7;
                    uint2 s2;
                    s2.x = (uint)f2bf(acc[n][j][0] + bs[0]) | ((uint)f2bf(acc[n][j][1] + bs[1]) << 16);
                    s2.y = (uint)f2bf(acc[n][j][2] + bs[2]) | ((uint)f2bf(acc[n][j][3] + bs[3]) << 16);
                    *(uint2*)(Pgo + ((size_t)((b * 8 + cg) * 130 + h + 1) * 130 + pxl + 1) * 8 + cs) = s2;
                } else if (co_g < 144) {
                    int p0 = co_g >> 1;
                    uint u0 = (uint)f2bf(acc[n][j][0] + bs[0]) | ((uint)f2bf(acc[n][j][1] + bs[1]) << 16);
                    uint u1 = (uint)f2bf(acc[n][j][2] + bs[2]) | ((uint)f2bf(acc[n][j][3] + bs[3]) << 16);
                    dyxp[(size_t)p0 * BHW + bhw] = u0;
                    dyxp[(size_t)(p0 + 1) * BHW + bhw] = u1;
                } else {
#pragma unroll
                    for (int r = 0; r < 4; r++) {
                        float f = 1.f / (1.f + __expf(-(acc[n][j][r] + bs[r])));
                        mpl[(size_t)(co_g - 144 + r) * BHW + bhw] = f2bf(f);
                    }
                }
            }
        }
    }
}

// ---------------------------------------------------------------------------
// Deform sampling kernel: one thread per (plane p = dg*9+tap, bhw). Pure TLP.
// ---------------------------------------------------------------------------
__global__ __launch_bounds__(256) void sample_k(
    const ushort* __restrict__ xg, const uint* __restrict__ dyxp,
    const ushort* __restrict__ mpl, ushort* __restrict__ vt) {
    int p = blockIdx.y;              // 0..71
    int dg = p / 9, tap = p - dg * 9;
    int ky = tap / 3, kx = tap - ky * 3;
    int bx = blockIdx.x;             // 0..511
    int bxs = (bx & 7) * 64 + (bx >> 3);   // XCD k -> image k
    int bhw = (bxs << 8) + threadIdx.x;
    int b = bhw >> 14;
    int h = (bhw >> 7) & 127;
    int w = bhw & 127;

    uint dyx = dyxp[(size_t)p * BHW + bhw];
    float m = bf2f(mpl[(size_t)p * BHW + bhw]);
    float dy = bf2f((ushort)(dyx & 0xffff));
    float dx = bf2f((ushort)(dyx >> 16));
    float py = dy + (float)(h + ky - 1);
    float px_ = dx + (float)(w + kx - 1);
    float fy = floorf(py), fx = floorf(px_);
    int y0 = (int)fy, x0 = (int)fx;
    int y1 = y0 + 1, x1 = x0 + 1;
    float ly = py - fy, lx = px_ - fx;
    bool vy0 = (unsigned)y0 < 128u, vy1 = (unsigned)y1 < 128u;
    bool vx0 = (unsigned)x0 < 128u, vx1 = (unsigned)x1 < 128u;
    float w00 = (vy0 && vx0) ? (1.f - ly) * (1.f - lx) * m : 0.f;
    float w01 = (vy0 && vx1) ? (1.f - ly) * lx * m : 0.f;
    float w10 = (vy1 && vx0) ? ly * (1.f - lx) * m : 0.f;
    float w11 = (vy1 && vx1) ? ly * lx * m : 0.f;
    int y0c = min(max(y0, 0), 127), y1c = min(max(y1, 0), 127);
    int x0c = min(max(x0, 0), 127), x1c = min(max(x1, 0), 127);
    const ushort* gb = xg + (((size_t)b * 8 + dg) << 17);
    uint4 q00 = *(const uint4*)(gb + ((y0c << 7) + x0c) * 8);
    uint4 q01 = *(const uint4*)(gb + ((y0c << 7) + x1c) * 8);
    uint4 q10 = *(const uint4*)(gb + ((y1c << 7) + x0c) * 8);
    uint4 q11 = *(const uint4*)(gb + ((y1c << 7) + x1c) * 8);
    const ushort* u00 = (const ushort*)&q00;
    const ushort* u01 = (const ushort*)&q01;
    const ushort* u10 = (const ushort*)&q10;
    const ushort* u11 = (const ushort*)&q11;
    uint pk[4];
#pragma unroll
    for (int c2 = 0; c2 < 4; c2++) {
        float v0 = w00 * bf2f(u00[2*c2])   + w01 * bf2f(u01[2*c2])
                 + w10 * bf2f(u10[2*c2])   + w11 * bf2f(u11[2*c2]);
        float v1 = w00 * bf2f(u00[2*c2+1]) + w01 * bf2f(u01[2*c2+1])
                 + w10 * bf2f(u10[2*c2+1]) + w11 * bf2f(u11[2*c2+1]);
        pk[c2] = (uint)f2bf(v0) | ((uint)f2bf(v1) << 16);
    }
    *(uint4*)(vt + ((size_t)p * BHW + bhw) * 8) = *(uint4*)pk;
}

// ---------------------------------------------------------------------------
// Deform GEMM: B sourced from materialized vt planes (HBM-roofline-bound).
// ---------------------------------------------------------------------------
__global__ __launch_bounds__(256, 3) void dgemm_k(
    const ushort* __restrict__ vt, const ushort* __restrict__ wa,
    const float* __restrict__ bias, float* __restrict__ out) {
    __shared__ ushort Al[64 * 64];
    __shared__ ushort Bt[64 * 64];
    int t = threadIdx.x;
    int orig = blockIdx.x;
    int blk = (orig & 7) * 256 + (orig >> 3);   // XCD = image
    int b = blk >> 8;
    int h = (blk >> 1) & 127;
    int w0 = (blk & 1) << 6;
    int lane = t & 63;
    int wv = t >> 6;
    int lg = lane >> 4;
    int lr = lane & 15;
    int rs = (lr & 7) << 4;
    int asw = ((lane & 7) ^ (lane >> 3)) << 4;
    const char* wab = (const char*)wa;
    int bhw0 = (b << 14) + (h << 7) + w0;

    f32x4 acc[4] = {f32x4{0,0,0,0}, f32x4{0,0,0,0}, f32x4{0,0,0,0}, f32x4{0,0,0,0}};

#pragma unroll 1
    for (int kk = 0; kk < 9; kk++) {
        __syncthreads();
#pragma unroll
        for (int a = 0; a < 2; a++) {
            int rb = wv * 16 + a * 8;
            const char* g = wab + (size_t)(rb + (lane >> 3)) * 1152 + kk * 128 + asw;
            __builtin_amdgcn_global_load_lds(
                (const __attribute__((address_space(1))) void*)g,
                (__attribute__((address_space(3))) void*)((char*)Al + rb * 128),
                16, 0, 0);
        }
        uint4 v0 = *(const uint4*)(vt + ((size_t)(wv * 9 + kk) * BHW + bhw0 + lane) * 8);
        uint4 v1 = *(const uint4*)(vt + ((size_t)((wv + 4) * 9 + kk) * BHW + bhw0 + lane) * 8);
        int swl = (lane & 7) << 4;
        *(uint4*)((char*)Bt + lane * 128 + ((wv * 16) ^ swl)) = v0;
        *(uint4*)((char*)Bt + lane * 128 + (((wv + 4) * 16) ^ swl)) = v1;
        __syncthreads();
        int ar = wv * 16 + lr;
        bf16x8 a0 = *(const bf16x8*)((char*)Al + ar * 128 + ((lg * 16) ^ rs));
        bf16x8 a1 = *(const bf16x8*)((char*)Al + ar * 128 + ((lg * 16 + 64) ^ rs));
#pragma unroll
        for (int j = 0; j < 4; j++) {
            int pr = j * 16 + lr;
            bf16x8 b0 = *(const bf16x8*)((char*)Bt + pr * 128 + ((lg * 16) ^ rs));
            bf16x8 b1 = *(const bf16x8*)((char*)Bt + pr * 128 + ((lg * 16 + 64) ^ rs));
            acc[j] = __builtin_amdgcn_mfma_f32_16x16x32_bf16(a0, b0, acc[j], 0, 0, 0);
            acc[j] = __builtin_amdgcn_mfma_f32_16x16x32_bf16(a1, b1, acc[j], 0, 0, 0);
        }
    }

    int co_g = wv * 16 + lg * 4;
    float bs[4];
#pragma unroll
    for (int r = 0; r < 4; r++) bs[r] = bias[co_g + r];
#pragma unroll
    for (int j = 0; j < 4; j++) {
        int hw = (h << 7) + w0 + j * 16 + lr;
#pragma unroll
        for (int r = 0; r < 4; r++) {
            out[((size_t)(b * 64 + co_g + r) << 14) + hw] = acc[j][r] + bs[r];
        }
    }
}

// ---------------------------------------------------------------------------
// Fallback (ws too small): all-register deform, fp16 path.
// ---------------------------------------------------------------------------
__global__ __launch_bounds__(256, 3) void deform_reg3_k(
    const ushort* __restrict__ xg, const uint* __restrict__ dyxp,
    const ushort* __restrict__ mpl, const ushort* __restrict__ wa,
    const float* __restrict__ bias, float* __restrict__ out) {
    int t = threadIdx.x;
    int orig = blockIdx.x;
    int blk = (orig & 7) * 256 + (orig >> 3);
    int b = blk >> 8;
    int h = (blk >> 1) & 127;
    int w0 = (blk & 1) << 6;
    int lane = t & 63;
    int wv = t >> 6;
    int lg = lane >> 4;
    int lr = lane & 15;
    int wabs = w0 + wv * 16 + lr;
    int bhw = (b << 14) + (h << 7) + wabs;

    uint dyxv[18];
    float mv[18];
#pragma unroll
    for (int c = 0; c < 18; c++) {
        int dg = ((c & 1) << 2) + lg;
        int tap = c >> 1;
        dyxv[c] = dyxp[(size_t)(dg * 9 + tap) * BHW + bhw];
        mv[c] = bf2f(mpl[(size_t)(dg * 9 + tap) * BHW + bhw]);
    }

    uint4 qg[2][4];
    f32x4 wt4[2];
    f16x8 afr[2][4];
    f32x4 acc[4] = {f32x4{0,0,0,0}, f32x4{0,0,0,0}, f32x4{0,0,0,0}, f32x4{0,0,0,0}};

#define DPRE(c) do {                                                            \
    const int tap = (c) >> 1;                                                   \
    const int ky = tap / 3;                                                     \
    const int kx = tap - ky * 3;                                                \
    int dg = (((c) & 1) << 2) + lg;                                             \
    uint dyx = dyxv[(c)];                                                       \
    float dy = bf2f((ushort)(dyx & 0xffff));                                    \
    float dx = bf2f((ushort)(dyx >> 16));                                       \
    float py = dy + (float)(h + ky - 1);                                        \
    float px_ = dx + (float)(wabs + kx - 1);                                    \
    float fy = floorf(py), fx = floorf(px_);                                    \
    int y0 = (int)fy, x0 = (int)fx;                                             \
    int y1 = y0 + 1, x1 = x0 + 1;                                               \
    int y0c = min(max(y0, 0), 127), y1c = min(max(y1, 0), 127);                 \
    int x0c = min(max(x0, 0), 127), x1c = min(max(x1, 0), 127);                 \
    const ushort* gb = xg + (((size_t)b * 8 + dg) << 17);                       \
    qg[(c) & 1][0] = *(const uint4*)(gb + ((y0c << 7) + x0c) * 8);              \
    qg[(c) & 1][1] = *(const uint4*)(gb + ((y0c << 7) + x1c) * 8);              \
    qg[(c) & 1][2] = *(const uint4*)(gb + ((y1c << 7) + x0c) * 8);              \
    qg[(c) & 1][3] = *(const uint4*)(gb + ((y1c << 7) + x1c) * 8);              \
    float ly = py - fy, lx = px_ - fx;                                          \
    bool vy0 = (unsigned)y0 < 128u, vy1 = (unsigned)y1 < 128u;                  \
    bool vx0 = (unsigned)x0 < 128u, vx1 = (unsigned)x1 < 128u;                  \
    float m = mv[(c)];                                                          \
    f32x4 wv4;                                                                  \
    wv4[0] = (vy0 && vx0) ? (1.f - ly) * (1.f - lx) * m : 0.f;                  \
    wv4[1] = (vy0 && vx1) ? (1.f - ly) * lx * m : 0.f;                          \
    wv4[2] = (vy1 && vx0) ? ly * (1.f - lx) * m : 0.f;                          \
    wv4[3] = (vy1 && vx1) ? ly * lx * m : 0.f;                                  \
    wt4[(c) & 1] = wv4;                                                         \
} while (0)

#define APRE(c) do {                                                            \
    const ushort* wac = wa + (c) * 32 + lg * 8;                                 \
    _Pragma("unroll")                                                           \
    for (int n = 0; n < 4; n++)                                                 \
        afr[(c) & 1][n] = *(const f16x8*)(wac + (size_t)(n * 16 + lr) * 576);   \
} while (0)

    DPRE(0);
    APRE(0);

#pragma unroll
    for (int c = 0; c < 18; c++) {
        if (c < 17) {
            DPRE(c + 1);
            APRE(c + 1);
        }
        __builtin_amdgcn_sched_barrier(0);
        f32x4 wc = wt4[c & 1];
        _Float16 wh0 = (_Float16)wc[0], wh1 = (_Float16)wc[1];
        _Float16 wh2 = (_Float16)wc[2], wh3 = (_Float16)wc[3];
        f16x2 w0p = {wh0, wh0}, w1p = {wh1, wh1}, w2p = {wh2, wh2}, w3p = {wh3, wh3};
        union { uint4 u4; uint u[4]; } c00, c01, c10, c11;
        c00.u4 = qg[c & 1][0]; c01.u4 = qg[c & 1][1];
        c10.u4 = qg[c & 1][2]; c11.u4 = qg[c & 1][3];
        union { f16x2 p[4]; f16x8 v; } bf;
#pragma unroll
        for (int c2 = 0; c2 < 4; c2++) {
            union { uint u; f16x2 h; } h00, h01, h10, h11;
            h00.u = c00.u[c2]; h01.u = c01.u[c2];
            h10.u = c10.u[c2]; h11.u = c11.u[c2];
            bf.p[c2] = h00.h * w0p + h01.h * w1p + h10.h * w2p + h11.h * w3p;
        }
#pragma unroll
        for (int n = 0; n < 4; n++)
            acc[n] = __builtin_amdgcn_mfma_f32_16x16x32_f16(afr[c & 1][n], bf.v, acc[n], 0, 0, 0);
    }
#undef DPRE
#undef APRE

    int hw = (h << 7) + wabs;
#pragma unroll
    for (int n = 0; n < 4; n++) {
        int co_g = n * 16 + lg * 4;
#pragma unroll
        for (int r = 0; r < 4; r++) {
            out[((size_t)(b * 64 + co_g + r) << 14) + hw] = acc[n][r] + bias[co_g + r];
        }
    }
}

extern "C" void kernel_launch(void* const* d_in, const int* in_sizes, int n_in,
                              void* d_out, int out_size, void* d_ws, size_t ws_size,
                              hipStream_t stream) {
    const float* cat_fea = (const float*)d_in[0];
    const float* f_fea   = (const float*)d_in[1];
    const float* w_off2d = (const float*)d_in[2];
    const float* b_off2d = (const float*)d_in[3];
    const float* w_coff  = (const float*)d_in[4];
    const float* b_coff  = (const float*)d_in[5];
    const float* w_dconv = (const float*)d_in[6];
    const float* b_dconv = (const float*)d_in[7];
    float* out = (float*)d_out;

    const size_t NEED_SG = 224837632ull;   // bytes for the sample+gemm path

    if (ws_size >= NEED_SG) {
        // ---- sample+gemm path. Pg1/Pgo alias into the (later dead) vt region ----
        ushort* xft  = (ushort*)d_ws;            // 8388608 ush (bf16)
        uint*   dyxp = (uint*)(xft + 8388608);   // 9437184 uints
        ushort* mpl  = (ushort*)(dyxp + 9437184);// 9437184 ush
        ushort* wa1  = mpl + 9437184;            // 36864
        ushort* wa2  = wa1 + 36864;              // 147456
        ushort* wad  = wa2 + 147456;             // 36864 (bf16)
        ushort* vt   = wad + 36864;              // 75497472 ush = 151 MB
        ushort* Pg1  = vt;                       // padded cat (8652800 ush), dead before sample_k
        ushort* Pgo  = vt + 8652800;             // padded off_feat, dead before sample_k

        halo_zero_k<<<(64 * 516 + 255) / 256, 256, 0, stream>>>(Pg1);
        halo_zero_k<<<(64 * 516 + 255) / 256, 256, 0, stream>>>(Pgo);
        to_gp_pad_k<<<2048, 256, 0, stream>>>(cat_fea, Pg1);
        to_gp_k<0><<<2048, 256, 0, stream>>>(f_fea, xft);
        prep_wa<0><<<(64 * 576 + 255) / 256, 256, 0, stream>>>(w_off2d, wa1, 64, 64);
        prep_wa<0><<<(256 * 576 + 255) / 256, 256, 0, stream>>>(w_coff, wa2, 216, 256);
        prep_wa<0><<<(64 * 576 + 255) / 256, 256, 0, stream>>>(w_dconv, wad, 64, 64);

        conv_pad_k<64, 0><<<dim3(1024, 1), 256, 0, stream>>>(Pg1, wa1, b_off2d, Pgo,
                                                             nullptr, nullptr, 64);
        conv_pad_k<128, 1><<<dim3(1024, 2), 256, 0, stream>>>(Pgo, wa2, b_coff, nullptr,
                                                              dyxp, mpl, 216);
        sample_k<<<dim3(512, 72), 256, 0, stream>>>(xft, dyxp, mpl, vt);
        dgemm_k<<<2048, 256, 0, stream>>>(vt, wad, b_dconv, out);
    } else {
        // ---- fallback: padded convs + all-register deform ----
        ushort* Pg1  = (ushort*)d_ws;            // 8652800 ush
        ushort* Pgo  = Pg1 + 8652800;            // 8652800 ush
        ushort* xft  = Pgo + 8652800;            // 8388608 (fp16)
        uint*   dyxp = (uint*)(xft + 8388608);   // 9437184 uints
        ushort* mpl  = (ushort*)(dyxp + 9437184);
        ushort* wa1  = mpl + 9437184;
        ushort* wa2  = wa1 + 36864;
        ushort* wad  = wa2 + 147456;             // fp16

        halo_zero_k<<<(64 * 516 + 255) / 256, 256, 0, stream>>>(Pg1);
        halo_zero_k<<<(64 * 516 + 255) / 256, 256, 0, stream>>>(Pgo);
        to_gp_pad_k<<<2048, 256, 0, stream>>>(cat_fea, Pg1);
        to_gp_k<1><<<2048, 256, 0, stream>>>(f_fea, xft);
        prep_wa<0><<<(64 * 576 + 255) / 256, 256, 0, stream>>>(w_off2d, wa1, 64, 64);
        prep_wa<0><<<(256 * 576 + 255) / 256, 256, 0, stream>>>(w_coff, wa2, 216, 256);
        prep_wa<1><<<(64 * 576 + 255) / 256, 256, 0, stream>>>(w_dconv, wad, 64, 64);

        conv_pad_k<64, 0><<<dim3(1024, 1), 256, 0, stream>>>(Pg1, wa1, b_off2d, Pgo,
                                                             nullptr, nullptr, 64);
        conv_pad_k<128, 1><<<dim3(1024, 2), 256, 0, stream>>>(Pgo, wa2, b_coff, nullptr,
                                                              dyxp, mpl, 216);
        deform_reg3_k<<<2048, 256, 0, stream>>>(xft, dyxp, mpl, wad, b_dconv, out);
    }
}

// Round 14
// 170.061 us; speedup vs baseline: 1.0913x; 1.0913x over previous
//
#include <hip/hip_runtime.h>
#include <math.h>

typedef __attribute__((ext_vector_type(4))) float f32x4;
typedef __attribute__((ext_vector_type(8))) short bf16x8;
typedef __attribute__((ext_vector_type(2))) _Float16 f16x2;
typedef __attribute__((ext_vector_type(8))) _Float16 f16x8;

#define HH 128
#define WW 128
#define HWSZ 16384
#define BHW 131072
#define BB 8

__device__ __forceinline__ float bf2f(ushort u) {
    union { uint i; float f; } x; x.i = ((uint)u) << 16; return x.f;
}
__device__ __forceinline__ ushort f2bf(float f) {
    union { float f; uint i; } x; x.f = f;
    uint r = (x.i + 0x7fffu + ((x.i >> 16) & 1u)) >> 16;
    return (ushort)r;
}
__device__ __forceinline__ ushort f2h_bits(float f) {
    union { _Float16 h; ushort u; } x; x.h = (_Float16)f; return x.u;
}

// Both NCHW fp32 inputs -> group-planar 16-bit in ONE launch (grid 4096).
// blk<2048: cat_fea -> y1 (bf16). else: f_fea -> y2 (bf16 or fp16 per f16b).
__global__ __launch_bounds__(256) void to_gp2_k(const float* __restrict__ x1,
                                                const float* __restrict__ x2,
                                                ushort* __restrict__ y1,
                                                ushort* __restrict__ y2,
                                                int f16b) {
    __shared__ ushort lds[64][66];
    int blk0 = blockIdx.x;
    int second = blk0 >> 11;
    int blk = blk0 & 2047;
    const float* x = second ? x2 : x1;
    ushort* y = second ? y2 : y1;
    int use16 = second & f16b;
    int b = blk >> 8;
    int hw0 = (blk & 255) << 6;
    int t = threadIdx.x;
    int lane = t & 63;
    int q = t >> 6;
#pragma unroll
    for (int i = 0; i < 16; i++) {
        int c = i * 4 + q;
        float v = x[((size_t)(b * 64 + c) << 14) + hw0 + lane];
        lds[c][lane] = use16 ? f2h_bits(v) : f2bf(v);
    }
    __syncthreads();
#pragma unroll
    for (int it = 0; it < 2; it++) {
        int id = it * 256 + t;
        int cg = id >> 6;
        int px = id & 63;
        uint pk[4];
#pragma unroll
        for (int j = 0; j < 4; j++)
            pk[j] = (uint)lds[cg * 8 + 2 * j][px] | ((uint)lds[cg * 8 + 2 * j + 1][px] << 16);
        *(uint4*)(y + ((((size_t)b * 8 + cg) << 14) + hw0 + px) * 8) = *(uint4*)pk;
    }
}

// All three weight preps in ONE launch. wa[co][r], r = kk*64+ci, zero-padded.
// Layout: [0,36864) wa1 (Co=64); [36864, 36864+147456) wa2 (Co=216, pad 256);
// rest wad (Co=64; fp16 if f16d).
__global__ __launch_bounds__(256) void prep_all_k(
    const float* __restrict__ w1, const float* __restrict__ w2,
    const float* __restrict__ wd, ushort* __restrict__ wa1,
    ushort* __restrict__ wa2, ushort* __restrict__ wad, int f16d) {
    int idx = blockIdx.x * 256 + threadIdx.x;
    const float* w; ushort* wa; int Co, use16 = 0;
    if (idx < 36864) {
        w = w1; wa = wa1; Co = 64;
    } else if (idx < 36864 + 147456) {
        idx -= 36864; w = w2; wa = wa2; Co = 216;
    } else {
        idx -= 36864 + 147456;
        if (idx >= 36864) return;
        w = wd; wa = wad; Co = 64; use16 = f16d;
    }
    int co = idx / 576, r = idx % 576;
    int kk = r >> 6, ci = r & 63;
    ushort v = 0;
    if (co < Co) {
        float f = w[(co * 64 + ci) * 9 + kk];
        v = use16 ? f2h_bits(f) : f2bf(f);
    }
    wa[idx] = v;
}

// ---------------------------------------------------------------------------
// 1-phase implicit-GEMM 3x3 conv, tile = 128 px (one image row) x COT co.
// BK=64 (one tap per step, 9 steps). A via global_load_lds (pre-swizzled src),
// B = row segment reg-staged with border predication. 32 KB LDS -> high
// blocks/CU (r11-r13 lesson: occupancy beats buffering for short K-steps).
// Waves whose entire co range is padding skip A-stage + MFMA (wave-uniform).
// MODE 0: output group-planar bf16. MODE 1: planar dyx + sigmoided mask.
// ---------------------------------------------------------------------------
template<int COT, int MODE>
__global__ __launch_bounds__(256, 4) void conv_gemm3_k(
    const ushort* __restrict__ xt, const ushort* __restrict__ wa,
    const float* __restrict__ bias, ushort* __restrict__ y,
    uint* __restrict__ dyxp, ushort* __restrict__ mpl, int Cout) {
    constexpr int WCO = COT / 4;     // co per wave
    constexpr int NN = WCO / 16;     // A fragment pairs per wave
    constexpr int NA = COT / 32;     // A gload_lds per wave
    __shared__ ushort Al[COT * 64];  // [COT co][64 ci], row 128 B, swizzled
    __shared__ ushort Bt[128 * 64];  // [128 px][64 ci], row 128 B, swizzled
    int t = threadIdx.x;
    int orig = blockIdx.x;
    int blk = (orig & 7) * 128 + (orig >> 3);   // bijective, 1024 = 8*128; XCD = image
    int b = blk >> 7;
    int h = blk & 127;
    int cot = blockIdx.y;
    int lane = t & 63;
    int wv = t >> 6;
    int lg = lane >> 4;
    int lr = lane & 15;
    int rs = (lr & 7) << 4;                      // read-side swizzle
    int asw = ((lane & 7) ^ (lane >> 3)) << 4;   // source pre-swizzle for gload_lds
    const char* wab = (const char*)wa;
    bool wactive = (cot * COT + wv * WCO) < Cout;   // wave-uniform tail skip

    f32x4 acc[NN][8];
#pragma unroll
    for (int n = 0; n < NN; n++)
#pragma unroll
        for (int j = 0; j < 8; j++) acc[n][j] = f32x4{0, 0, 0, 0};

#pragma unroll 1
    for (int kk = 0; kk < 9; kk++) {
        int ky = kk / 3;
        int kx = kk - ky * 3;
        __syncthreads();
        // ---- stage A (own rows only; skipped by fully-padded waves) ----
        if (wactive) {
#pragma unroll
            for (int a = 0; a < NA; a++) {
                int rb = wv * WCO + a * 8;
                const char* g = wab + (size_t)(cot * COT + rb + (lane >> 3)) * 1152 + kk * 128 + asw;
                __builtin_amdgcn_global_load_lds(
                    (const __attribute__((address_space(1))) void*)g,
                    (__attribute__((address_space(3))) void*)((char*)Al + rb * 128),
                    16, 0, 0);
            }
        }
        // ---- stage B: row hy, 128 px x 8 cg, predicated borders (all threads) ----
        int hy = h + ky - 1;
        bool vr = (unsigned)hy < 128u;
#pragma unroll
        for (int i = 0; i < 4; i++) {
            int id = i * 256 + t;
            int px = id & 127;
            int cg = id >> 7;
            int wx = px + kx - 1;
            uint4 v = {0u, 0u, 0u, 0u};
            if (vr && (unsigned)wx < 128u)
                v = *(const uint4*)(xt + ((((size_t)b * 8 + cg) << 14) + (hy << 7) + wx) * 8);
            *(uint4*)((char*)Bt + px * 128 + ((cg * 16) ^ ((px & 7) << 4))) = v;
        }
        __syncthreads();
        // ---- compute (skipped by fully-padded waves) ----
        if (wactive) {
            bf16x8 a0[NN], a1[NN];
#pragma unroll
            for (int n = 0; n < NN; n++) {
                int ar = wv * WCO + n * 16 + lr;
                a0[n] = *(const bf16x8*)((char*)Al + ar * 128 + ((lg * 16) ^ rs));
                a1[n] = *(const bf16x8*)((char*)Al + ar * 128 + ((lg * 16 + 64) ^ rs));
            }
#pragma unroll
            for (int j = 0; j < 8; j++) {
                int pr = j * 16 + lr;
                bf16x8 b0 = *(const bf16x8*)((char*)Bt + pr * 128 + ((lg * 16) ^ rs));
                bf16x8 b1 = *(const bf16x8*)((char*)Bt + pr * 128 + ((lg * 16 + 64) ^ rs));
#pragma unroll
                for (int n = 0; n < NN; n++) {
                    acc[n][j] = __builtin_amdgcn_mfma_f32_16x16x32_bf16(a0[n], b0, acc[n][j], 0, 0, 0);
                    acc[n][j] = __builtin_amdgcn_mfma_f32_16x16x32_bf16(a1[n], b1, acc[n][j], 0, 0, 0);
                }
            }
        }
    }

    // ---- epilogue: co = cot*COT + wv*WCO + n*16 + lg*4 + r, px = j*16 + lr ----
#pragma unroll
    for (int n = 0; n < NN; n++) {
        int co_g = cot * COT + wv * WCO + n * 16 + lg * 4;
        if (co_g < Cout) {
            float bs[4];
#pragma unroll
            for (int r = 0; r < 4; r++) bs[r] = bias[co_g + r];
#pragma unroll
            for (int j = 0; j < 8; j++) {
                int pxl = j * 16 + lr;
                int hw = (h << 7) + pxl;
                int bhw = (b << 14) + hw;
                if (MODE == 0) {
                    int cg = co_g >> 3, cs = co_g & 7;
                    uint2 s2;
                    s2.x = (uint)f2bf(acc[n][j][0] + bs[0]) | ((uint)f2bf(acc[n][j][1] + bs[1]) << 16);
                    s2.y = (uint)f2bf(acc[n][j][2] + bs[2]) | ((uint)f2bf(acc[n][j][3] + bs[3]) << 16);
                    *(uint2*)(y + ((((size_t)b * 8 + cg) << 14) + hw) * 8 + cs) = s2;
                } else if (co_g < 144) {
                    int p0 = co_g >> 1;
                    uint u0 = (uint)f2bf(acc[n][j][0] + bs[0]) | ((uint)f2bf(acc[n][j][1] + bs[1]) << 16);
                    uint u1 = (uint)f2bf(acc[n][j][2] + bs[2]) | ((uint)f2bf(acc[n][j][3] + bs[3]) << 16);
                    dyxp[(size_t)p0 * BHW + bhw] = u0;
                    dyxp[(size_t)(p0 + 1) * BHW + bhw] = u1;
                } else {
#pragma unroll
                    for (int r = 0; r < 4; r++) {
                        float f = 1.f / (1.f + __expf(-(acc[n][j][r] + bs[r])));
                        mpl[(size_t)(co_g - 144 + r) * BHW + bhw] = f2bf(f);
                    }
                }
            }
        }
    }
}

// ---------------------------------------------------------------------------
// Deform sampling kernel: one thread per (plane p = dg*9+tap, bhw). Pure TLP.
// ---------------------------------------------------------------------------
__global__ __launch_bounds__(256) void sample_k(
    const ushort* __restrict__ xg, const uint* __restrict__ dyxp,
    const ushort* __restrict__ mpl, ushort* __restrict__ vt) {
    int p = blockIdx.y;              // 0..71
    int dg = p / 9, tap = p - dg * 9;
    int ky = tap / 3, kx = tap - ky * 3;
    int bx = blockIdx.x;             // 0..511
    int bxs = (bx & 7) * 64 + (bx >> 3);   // XCD k -> image k
    int bhw = (bxs << 8) + threadIdx.x;
    int b = bhw >> 14;
    int h = (bhw >> 7) & 127;
    int w = bhw & 127;

    uint dyx = dyxp[(size_t)p * BHW + bhw];
    float m = bf2f(mpl[(size_t)p * BHW + bhw]);
    float dy = bf2f((ushort)(dyx & 0xffff));
    float dx = bf2f((ushort)(dyx >> 16));
    float py = dy + (float)(h + ky - 1);
    float px_ = dx + (float)(w + kx - 1);
    float fy = floorf(py), fx = floorf(px_);
    int y0 = (int)fy, x0 = (int)fx;
    int y1 = y0 + 1, x1 = x0 + 1;
    float ly = py - fy, lx = px_ - fx;
    bool vy0 = (unsigned)y0 < 128u, vy1 = (unsigned)y1 < 128u;
    bool vx0 = (unsigned)x0 < 128u, vx1 = (unsigned)x1 < 128u;
    float w00 = (vy0 && vx0) ? (1.f - ly) * (1.f - lx) * m : 0.f;
    float w01 = (vy0 && vx1) ? (1.f - ly) * lx * m : 0.f;
    float w10 = (vy1 && vx0) ? ly * (1.f - lx) * m : 0.f;
    float w11 = (vy1 && vx1) ? ly * lx * m : 0.f;
    int y0c = min(max(y0, 0), 127), y1c = min(max(y1, 0), 127);
    int x0c = min(max(x0, 0), 127), x1c = min(max(x1, 0), 127);
    const ushort* gb = xg + (((size_t)b * 8 + dg) << 17);
    uint4 q00 = *(const uint4*)(gb + ((y0c << 7) + x0c) * 8);
    uint4 q01 = *(const uint4*)(gb + ((y0c << 7) + x1c) * 8);
    uint4 q10 = *(const uint4*)(gb + ((y1c << 7) + x0c) * 8);
    uint4 q11 = *(const uint4*)(gb + ((y1c << 7) + x1c) * 8);
    const ushort* u00 = (const ushort*)&q00;
    const ushort* u01 = (const ushort*)&q01;
    const ushort* u10 = (const ushort*)&q10;
    const ushort* u11 = (const ushort*)&q11;
    uint pk[4];
#pragma unroll
    for (int c2 = 0; c2 < 4; c2++) {
        float v0 = w00 * bf2f(u00[2*c2])   + w01 * bf2f(u01[2*c2])
                 + w10 * bf2f(u10[2*c2])   + w11 * bf2f(u11[2*c2]);
        float v1 = w00 * bf2f(u00[2*c2+1]) + w01 * bf2f(u01[2*c2+1])
                 + w10 * bf2f(u10[2*c2+1]) + w11 * bf2f(u11[2*c2+1]);
        pk[c2] = (uint)f2bf(v0) | ((uint)f2bf(v1) << 16);
    }
    *(uint4*)(vt + ((size_t)p * BHW + bhw) * 8) = *(uint4*)pk;
}

// ---------------------------------------------------------------------------
// Deform GEMM: B sourced from materialized vt planes (HBM-roofline-bound).
// ---------------------------------------------------------------------------
__global__ __launch_bounds__(256, 3) void dgemm_k(
    const ushort* __restrict__ vt, const ushort* __restrict__ wa,
    const float* __restrict__ bias, float* __restrict__ out) {
    __shared__ ushort Al[64 * 64];
    __shared__ ushort Bt[64 * 64];
    int t = threadIdx.x;
    int orig = blockIdx.x;
    int blk = (orig & 7) * 256 + (orig >> 3);   // XCD = image
    int b = blk >> 8;
    int h = (blk >> 1) & 127;
    int w0 = (blk & 1) << 6;
    int lane = t & 63;
    int wv = t >> 6;
    int lg = lane >> 4;
    int lr = lane & 15;
    int rs = (lr & 7) << 4;
    int asw = ((lane & 7) ^ (lane >> 3)) << 4;
    const char* wab = (const char*)wa;
    int bhw0 = (b << 14) + (h << 7) + w0;

    f32x4 acc[4] = {f32x4{0,0,0,0}, f32x4{0,0,0,0}, f32x4{0,0,0,0}, f32x4{0,0,0,0}};

#pragma unroll 1
    for (int kk = 0; kk < 9; kk++) {
        __syncthreads();
#pragma unroll
        for (int a = 0; a < 2; a++) {
            int rb = wv * 16 + a * 8;
            const char* g = wab + (size_t)(rb + (lane >> 3)) * 1152 + kk * 128 + asw;
            __builtin_amdgcn_global_load_lds(
                (const __attribute__((address_space(1))) void*)g,
                (__attribute__((address_space(3))) void*)((char*)Al + rb * 128),
                16, 0, 0);
        }
        uint4 v0 = *(const uint4*)(vt + ((size_t)(wv * 9 + kk) * BHW + bhw0 + lane) * 8);
        uint4 v1 = *(const uint4*)(vt + ((size_t)((wv + 4) * 9 + kk) * BHW + bhw0 + lane) * 8);
        int swl = (lane & 7) << 4;
        *(uint4*)((char*)Bt + lane * 128 + ((wv * 16) ^ swl)) = v0;
        *(uint4*)((char*)Bt + lane * 128 + (((wv + 4) * 16) ^ swl)) = v1;
        __syncthreads();
        int ar = wv * 16 + lr;
        bf16x8 a0 = *(const bf16x8*)((char*)Al + ar * 128 + ((lg * 16) ^ rs));
        bf16x8 a1 = *(const bf16x8*)((char*)Al + ar * 128 + ((lg * 16 + 64) ^ rs));
#pragma unroll
        for (int j = 0; j < 4; j++) {
            int pr = j * 16 + lr;
            bf16x8 b0 = *(const bf16x8*)((char*)Bt + pr * 128 + ((lg * 16) ^ rs));
            bf16x8 b1 = *(const bf16x8*)((char*)Bt + pr * 128 + ((lg * 16 + 64) ^ rs));
            acc[j] = __builtin_amdgcn_mfma_f32_16x16x32_bf16(a0, b0, acc[j], 0, 0, 0);
            acc[j] = __builtin_amdgcn_mfma_f32_16x16x32_bf16(a1, b1, acc[j], 0, 0, 0);
        }
    }

    int co_g = wv * 16 + lg * 4;
    float bs[4];
#pragma unroll
    for (int r = 0; r < 4; r++) bs[r] = bias[co_g + r];
#pragma unroll
    for (int j = 0; j < 4; j++) {
        int hw = (h << 7) + w0 + j * 16 + lr;
#pragma unroll
        for (int r = 0; r < 4; r++) {
            out[((size_t)(b * 64 + co_g + r) << 14) + hw] = acc[j][r] + bs[r];
        }
    }
}

// ---------------------------------------------------------------------------
// Fallback (ws too small): all-register deform, fp16 path.
// ---------------------------------------------------------------------------
__global__ __launch_bounds__(256, 3) void deform_reg3_k(
    const ushort* __restrict__ xg, const uint* __restrict__ dyxp,
    const ushort* __restrict__ mpl, const ushort* __restrict__ wa,
    const float* __restrict__ bias, float* __restrict__ out) {
    int t = threadIdx.x;
    int orig = blockIdx.x;
    int blk = (orig & 7) * 256 + (orig >> 3);
    int b = blk >> 8;
    int h = (blk >> 1) & 127;
    int w0 = (blk & 1) << 6;
    int lane = t & 63;
    int wv = t >> 6;
    int lg = lane >> 4;
    int lr = lane & 15;
    int wabs = w0 + wv * 16 + lr;
    int bhw = (b << 14) + (h << 7) + wabs;

    uint dyxv[18];
    float mv[18];
#pragma unroll
    for (int c = 0; c < 18; c++) {
        int dg = ((c & 1) << 2) + lg;
        int tap = c >> 1;
        dyxv[c] = dyxp[(size_t)(dg * 9 + tap) * BHW + bhw];
        mv[c] = bf2f(mpl[(size_t)(dg * 9 + tap) * BHW + bhw]);
    }

    uint4 qg[2][4];
    f32x4 wt4[2];
    f16x8 afr[2][4];
    f32x4 acc[4] = {f32x4{0,0,0,0}, f32x4{0,0,0,0}, f32x4{0,0,0,0}, f32x4{0,0,0,0}};

#define DPRE(c) do {                                                            \
    const int tap = (c) >> 1;                                                   \
    const int ky = tap / 3;                                                     \
    const int kx = tap - ky * 3;                                                \
    int dg = (((c) & 1) << 2) + lg;                                             \
    uint dyx = dyxv[(c)];                                                       \
    float dy = bf2f((ushort)(dyx & 0xffff));                                    \
    float dx = bf2f((ushort)(dyx >> 16));                                       \
    float py = dy + (float)(h + ky - 1);                                        \
    float px_ = dx + (float)(wabs + kx - 1);                                    \
    float fy = floorf(py), fx = floorf(px_);                                    \
    int y0 = (int)fy, x0 = (int)fx;                                             \
    int y1 = y0 + 1, x1 = x0 + 1;                                               \
    int y0c = min(max(y0, 0), 127), y1c = min(max(y1, 0), 127);                 \
    int x0c = min(max(x0, 0), 127), x1c = min(max(x1, 0), 127);                 \
    const ushort* gb = xg + (((size_t)b * 8 + dg) << 17);                       \
    qg[(c) & 1][0] = *(const uint4*)(gb + ((y0c << 7) + x0c) * 8);              \
    qg[(c) & 1][1] = *(const uint4*)(gb + ((y0c << 7) + x1c) * 8);              \
    qg[(c) & 1][2] = *(const uint4*)(gb + ((y1c << 7) + x0c) * 8);              \
    qg[(c) & 1][3] = *(const uint4*)(gb + ((y1c << 7) + x1c) * 8);              \
    float ly = py - fy, lx = px_ - fx;                                          \
    bool vy0 = (unsigned)y0 < 128u, vy1 = (unsigned)y1 < 128u;                  \
    bool vx0 = (unsigned)x0 < 128u, vx1 = (unsigned)x1 < 128u;                  \
    float m = mv[(c)];                                                          \
    f32x4 wv4;                                                                  \
    wv4[0] = (vy0 && vx0) ? (1.f - ly) * (1.f - lx) * m : 0.f;                  \
    wv4[1] = (vy0 && vx1) ? (1.f - ly) * lx * m : 0.f;                          \
    wv4[2] = (vy1 && vx0) ? ly * (1.f - lx) * m : 0.f;                          \
    wv4[3] = (vy1 && vx1) ? ly * lx * m : 0.f;                                  \
    wt4[(c) & 1] = wv4;                                                         \
} while (0)

#define APRE(c) do {                                                            \
    const ushort* wac = wa + (c) * 32 + lg * 8;                                 \
    _Pragma("unroll")                                                           \
    for (int n = 0; n < 4; n++)                                                 \
        afr[(c) & 1][n] = *(const f16x8*)(wac + (size_t)(n * 16 + lr) * 576);   \
} while (0)

    DPRE(0);
    APRE(0);

#pragma unroll
    for (int c = 0; c < 18; c++) {
        if (c < 17) {
            DPRE(c + 1);
            APRE(c + 1);
        }
        __builtin_amdgcn_sched_barrier(0);
        f32x4 wc = wt4[c & 1];
        _Float16 wh0 = (_Float16)wc[0], wh1 = (_Float16)wc[1];
        _Float16 wh2 = (_Float16)wc[2], wh3 = (_Float16)wc[3];
        f16x2 w0p = {wh0, wh0}, w1p = {wh1, wh1}, w2p = {wh2, wh2}, w3p = {wh3, wh3};
        union { uint4 u4; uint u[4]; } c00, c01, c10, c11;
        c00.u4 = qg[c & 1][0]; c01.u4 = qg[c & 1][1];
        c10.u4 = qg[c & 1][2]; c11.u4 = qg[c & 1][3];
        union { f16x2 p[4]; f16x8 v; } bf;
#pragma unroll
        for (int c2 = 0; c2 < 4; c2++) {
            union { uint u; f16x2 h; } h00, h01, h10, h11;
            h00.u = c00.u[c2]; h01.u = c01.u[c2];
            h10.u = c10.u[c2]; h11.u = c11.u[c2];
            bf.p[c2] = h00.h * w0p + h01.h * w1p + h10.h * w2p + h11.h * w3p;
        }
#pragma unroll
        for (int n = 0; n < 4; n++)
            acc[n] = __builtin_amdgcn_mfma_f32_16x16x32_f16(afr[c & 1][n], bf.v, acc[n], 0, 0, 0);
    }
#undef DPRE
#undef APRE

    int hw = (h << 7) + wabs;
#pragma unroll
    for (int n = 0; n < 4; n++) {
        int co_g = n * 16 + lg * 4;
#pragma unroll
        for (int r = 0; r < 4; r++) {
            out[((size_t)(b * 64 + co_g + r) << 14) + hw] = acc[n][r] + bias[co_g + r];
        }
    }
}

extern "C" void kernel_launch(void* const* d_in, const int* in_sizes, int n_in,
                              void* d_out, int out_size, void* d_ws, size_t ws_size,
                              hipStream_t stream) {
    const float* cat_fea = (const float*)d_in[0];
    const float* f_fea   = (const float*)d_in[1];
    const float* w_off2d = (const float*)d_in[2];
    const float* b_off2d = (const float*)d_in[3];
    const float* w_coff  = (const float*)d_in[4];
    const float* b_coff  = (const float*)d_in[5];
    const float* w_dconv = (const float*)d_in[6];
    const float* b_dconv = (const float*)d_in[7];
    float* out = (float*)d_out;

    const size_t NEED_SG = 224837632ull;   // bytes for the sample+gemm path
    const int PREP_N = (36864 + 147456 + 36864 + 255) / 256;

    if (ws_size >= NEED_SG) {
        // ---- sample+gemm path ----
        ushort* xft  = (ushort*)d_ws;            // 8388608 ush (bf16)
        uint*   dyxp = (uint*)(xft + 8388608);   // 9437184 uints
        ushort* mpl  = (ushort*)(dyxp + 9437184);// 9437184 ush
        ushort* wa1  = mpl + 9437184;            // 36864
        ushort* wa2  = wa1 + 36864;              // 147456
        ushort* wad  = wa2 + 147456;             // 36864 (bf16)
        ushort* vt   = wad + 36864;              // 75497472 ush = 151 MB
        ushort* x1t      = vt;                   // aliased: dead before sample_k
        ushort* off_feat = vt + 8388608;         // aliased: dead before sample_k

        to_gp2_k<<<4096, 256, 0, stream>>>(cat_fea, f_fea, x1t, xft, 0);
        prep_all_k<<<PREP_N, 256, 0, stream>>>(w_off2d, w_coff, w_dconv,
                                               wa1, wa2, wad, 0);

        conv_gemm3_k<64, 0><<<dim3(1024, 1), 256, 0, stream>>>(x1t, wa1, b_off2d, off_feat,
                                                               nullptr, nullptr, 64);
        conv_gemm3_k<128, 1><<<dim3(1024, 2), 256, 0, stream>>>(off_feat, wa2, b_coff, nullptr,
                                                                dyxp, mpl, 216);
        sample_k<<<dim3(512, 72), 256, 0, stream>>>(xft, dyxp, mpl, vt);
        dgemm_k<<<2048, 256, 0, stream>>>(vt, wad, b_dconv, out);
    } else {
        // ---- fallback: all-register deform ----
        ushort* x1t      = (ushort*)d_ws;
        ushort* xft      = x1t + 8388608;              // fp16
        ushort* off_feat = xft + 8388608;
        uint*   dyxp     = (uint*)(off_feat + 8388608);
        ushort* mpl      = (ushort*)(dyxp + 9437184);
        ushort* wa1      = mpl + 9437184;
        ushort* wa2      = wa1 + 36864;
        ushort* wad      = wa2 + 147456;               // fp16

        to_gp2_k<<<4096, 256, 0, stream>>>(cat_fea, f_fea, x1t, xft, 1);
        prep_all_k<<<PREP_N, 256, 0, stream>>>(w_off2d, w_coff, w_dconv,
                                               wa1, wa2, wad, 1);

        conv_gemm3_k<64, 0><<<dim3(1024, 1), 256, 0, stream>>>(x1t, wa1, b_off2d, off_feat,
                                                               nullptr, nullptr, 64);
        conv_gemm3_k<128, 1><<<dim3(1024, 2), 256, 0, stream>>>(off_feat, wa2, b_coff, nullptr,
                                                                dyxp, mpl, 216);
        deform_reg3_k<<<2048, 256, 0, stream>>>(xft, dyxp, mpl, wad, b_dconv, out);
    }
}